// Round 18
// baseline (274.667 us; speedup 1.0000x reference)
//
#include <hip/hip_runtime.h>
#include <stdint.h>

#define B_ROWS 2048
#define D2_DIM 256
#define D_DIM 128
#define M_ITEMS 100000
#define M_PAD 100352           // 196 * 512
#define BN_EPS_F 1e-5f
#define COS_EPS_F 1e-6f
#define LEAKY_F 0.01f

#define BNI 128                // items per tile
#define BK 32                  // K per stage
#define SUPER 4                // item tiles per block -> 512 items/block
#define BROWS 64               // rows per block

typedef __bf16 bf16x8 __attribute__((ext_vector_type(8)));
typedef float f32x4 __attribute__((ext_vector_type(4)));

// bf16 hi/lo split planes (device globals; rebuilt every call)
__device__ unsigned short g_Aph[B_ROWS * D_DIM];
__device__ unsigned short g_Apl[B_ROWS * D_DIM];
__device__ unsigned short g_Bph[M_PAD * D_DIM];
__device__ unsigned short g_Bpl[M_PAD * D_DIM];

__device__ __forceinline__ unsigned bf16_rne(float f) {
  unsigned u = __float_as_uint(f);
  return (u + 0x7fffu + ((u >> 16) & 1u)) >> 16;
}
__device__ __forceinline__ void split_bf16(float v, unsigned short& hi, unsigned short& lo) {
  unsigned h = bf16_rne(v);
  float hf = __uint_as_float(h << 16);
  unsigned l = bf16_rne(v - hf);   // exact residual
  hi = (unsigned short)h; lo = (unsigned short)l;
}
__device__ __forceinline__ void gload16(const void* g, void* l) {
  __builtin_amdgcn_global_load_lds(
      (const __attribute__((address_space(1))) void*)g,
      (__attribute__((address_space(3))) void*)l, 16, 0, 0);
}
__device__ __forceinline__ unsigned long long pack_key(float v, int idx) {
  unsigned u = __float_as_uint(v);
  u = (u & 0x80000000u) ? ~u : (u | 0x80000000u);
  return ((unsigned long long)u << 32) | (unsigned)(~(unsigned)idx);
}

// ---------- kernel 1: h = item_feature @ W + b ----------
__global__ void k_gemm1(const float* __restrict__ A, const float* __restrict__ W,
                        const float* __restrict__ bias, float* __restrict__ h) {
  __shared__ float arow[D2_DIM];
  const int r = blockIdx.x;
  const int c = threadIdx.x;  // 128
  arow[c] = A[r * D2_DIM + c];
  arow[c + 128] = A[r * D2_DIM + c + 128];
  __syncthreads();
  float acc = 0.f;
#pragma unroll 8
  for (int k = 0; k < D2_DIM; k++) acc = fmaf(arow[k], W[k * D_DIM + c], acc);
  h[r * D_DIM + c] = acc + bias[c];
}

// ---------- kernel 2: per-column mean/var -> scale/shift ----------
__global__ void k_bnstats(const float* __restrict__ h, const float* __restrict__ gamma,
                          const float* __restrict__ beta, float* __restrict__ scale,
                          float* __restrict__ shift) {
  const int c = blockIdx.x;
  const int t = threadIdx.x;  // 256
  double s = 0.0, sq = 0.0;
  for (int r = t; r < B_ROWS; r += 256) {
    double v = (double)h[r * D_DIM + c];
    s += v; sq += v * v;
  }
  __shared__ double ls[256], lq[256];
  ls[t] = s; lq[t] = sq;
  __syncthreads();
  for (int off = 128; off; off >>= 1) {
    if (t < off) { ls[t] += ls[t + off]; lq[t] += lq[t + off]; }
    __syncthreads();
  }
  if (t == 0) {
    double mean = ls[0] / (double)B_ROWS;
    double var = lq[0] / (double)B_ROWS - mean * mean;
    float sc = (float)((double)gamma[c] / sqrt(var + (double)BN_EPS_F));
    scale[c] = sc;
    shift[c] = beta[c] - (float)mean * sc;
  }
}

// ---------- kernel 3: uf = leaky(bn(h)) -> bf16 hi/lo planes ----------
__global__ void k_norm_split(const float* __restrict__ h, const float* __restrict__ scale,
                             const float* __restrict__ shift) {
  int i = blockIdx.x * 256 + threadIdx.x;
  if (i >= B_ROWS * D_DIM) return;
  int c = i & (D_DIM - 1);
  float v = fmaf(h[i], scale[c], shift[c]);
  v = v >= 0.f ? v : LEAKY_F * v;
  unsigned short hi, lo;
  split_bf16(v, hi, lo);
  g_Aph[i] = hi; g_Apl[i] = lo;
}

// ---------- kernel 4: all_items -> bf16 hi/lo planes (pad rows zeroed) ----------
__global__ void k_build_items(const float* __restrict__ items) {
  long long t = (long long)blockIdx.x * 256 + threadIdx.x;
  long long base = t * 4;
  if (base >= (long long)M_PAD * D_DIM) return;
  float4 v;
  if (base < (long long)M_ITEMS * D_DIM) v = *(const float4*)&items[base];
  else v = make_float4(0.f, 0.f, 0.f, 0.f);
  ushort4 hv, lv;
  split_bf16(v.x, hv.x, lv.x);
  split_bf16(v.y, hv.y, lv.y);
  split_bf16(v.z, hv.z, lv.z);
  split_bf16(v.w, hv.w, lv.w);
  *(ushort4*)&g_Bph[base] = hv;
  *(ushort4*)&g_Bpl[base] = lv;
}

// ---------- kernel 5: init argmax keys ----------
__global__ void k_init(unsigned long long* __restrict__ keys) {
  int i = blockIdx.x * blockDim.x + threadIdx.x;
  if (i < B_ROWS) keys[i] = 0ull;
}

// ---------- kernel 6: MFMA scores + fused argmax ----------
// vs R17 (226us): R17 behaved as SUM of pipes (MFMA 1.9k + VALU 1.9k + DS
// 1.2k ~ 5.5k cyc/step) -- too little TLP at 2 waves/SIMD, and the 3-term
// algorithm's ~190 persistent regs blocked more waves. Fix: shrink the wave
// tile to 32x32 (acc 16 AGPR + bestv 8 AGPR + ah 32 arch ~ 110 regs) ->
// 512-thr blocks, 8 waves, waves_per_eu(4,4) = 4 waves/SIMD, 16 waves/CU.
// Block tile 64 rows x 128 items, SUPER=4. LDS 64KB (3x16KB B ring + 16KB
// A-lo) -> 2 blocks/CU. Same proven machinery: counted vmcnt (now 2 loads/
// thread/stage -> vmcnt(2)), 2-ahead prefetch, both-sides swizzles,
// deferred-selection argmax (q 0..7, one u32 sel), AGPR-pinned bestv.
// Prologue globals (ah) issue FIRST + sched_barrier so the in-loop vmcnt
// queue holds only ring loads (R7 lesson).
__global__
__attribute__((amdgpu_flat_work_group_size(512, 512), amdgpu_waves_per_eu(4, 4)))
void k_scores_mfma(unsigned long long* __restrict__ keys) {
  __shared__ __align__(16) char smem[65536];   // 3x16KB B ring + 16KB A-lo
  char* sAlo = smem + 49152;

  const int tid = threadIdx.x;
  const int l = tid & 63;
  const int w = tid >> 6;      // 0..7
  const int wm = w >> 2;       // row half (0..1) of 64 rows
  const int wn = w & 3;        // item quarter (0..3) of 128 items
  const int rowbase = blockIdx.x * BROWS;        // row-block FAST -> B locality
  const int chunk = blockIdx.y * (SUPER * BNI);  // item chunk slow
  const int lrow = l & 15;
  const int lkg = l >> 4;      // 0..3

  // per-thread constant staging offsets (one slot per plane per thread)
  const int tb = (tid >> 2) * 256 + (((tid & 3) ^ ((tid >> 3) & 3)) * 16);
  const int ldst = tid * 16;   // linear LDS dest within plane (512 slots)
  const char* gBh = (const char*)g_Bph;
  const char* gBl = (const char*)g_Bpl;

  // ---- B stage (hi 8KB @ buf, lo 8KB @ buf+8192), source pre-swizzled ----
  auto STAGEB = [&](int itembase, int ks, char* buf) {
    const size_t ub = (size_t)itembase * 256 + (size_t)ks * 2;
    gload16(gBh + ub + tb, buf + ldst);
    gload16(gBl + ub + tb, buf + 8192 + ldst);
  };

  // ---- prologue ----
  // 1) ah -> regs FIRST (drains at step 0's vmcnt; never pollutes the loop)
  bf16x8 ah[2][4];
  const int ar = rowbase + wm * 32 + lrow;
#pragma unroll
  for (int mi = 0; mi < 2; mi++)
#pragma unroll
    for (int kf = 0; kf < 4; kf++)
      ah[mi][kf] = *(const bf16x8*)&g_Aph[(size_t)(ar + mi * 16) * D_DIM + kf * 32 + lkg * 8];
  __builtin_amdgcn_sched_barrier(0);
  // 2) A-lo -> LDS: 1024 slots (row=s>>4, sig=s&15 holds quad sig^(row&15))
#pragma unroll
  for (int rep = 0; rep < 2; rep++) {
    const int s = tid + rep * 512;
    gload16(g_Apl + (size_t)(rowbase + (s >> 4)) * D_DIM
                  + ((s & 15) ^ ((s >> 4) & 15)) * 8,
            sAlo + s * 16);
  }
  // 3) ring stages 0,1
  STAGEB(chunk, 0, smem);
  STAGEB(chunk, BK, smem + 16384);

  // ds_read base for B: imm covers buf*16384 + plane*8192 + ni*1024
  char* lbase = smem + wn * 2048 + lrow * 64 + ((lkg ^ ((lrow >> 1) & 3)) << 4);

  // deferred-selection argmax state; bestv pinned to AGPRs
  float bestv[2][4];
  unsigned sel = 0u;           // 8 x 4-bit (s*4+ni) codes
#pragma unroll
  for (int mi = 0; mi < 2; mi++)
#pragma unroll
    for (int reg = 0; reg < 4; reg++)
      asm volatile("v_accvgpr_write_b32 %0, %1"
                   : "=a"(bestv[mi][reg]) : "v"(-3.0e38f));

  f32x4 acc[2][2];
#pragma unroll
  for (int mi = 0; mi < 2; mi++)
#pragma unroll
    for (int ni = 0; ni < 2; ni++) acc[mi][ni] = (f32x4)(0.0f);

#pragma unroll
  for (int s = 0; s < SUPER; s++) {
    const int itembase = chunk + s * BNI;
#pragma unroll
    for (int kf = 0; kf < 4; kf++) {
      const int j = s * 4 + kf;
      // own stage-j landed (stage j+1's 2 loads stay in flight)
      asm volatile("s_waitcnt vmcnt(2)" ::: "memory");
      __builtin_amdgcn_s_barrier();   // all waves' stage-j landed; buf[(j+2)%3] free
      {
        const int q = j + 2;          // prefetch 2 steps ahead (tail: dummy reload)
        const int qt = (q >> 2) & (SUPER - 1);
        STAGEB(chunk + qt * BNI, (q & 3) * BK, smem + (q % 3) * 16384);
      }
      const int jb = (j % 3) * 16384;   // compile-time (loop fully unrolled)
      bf16x8 bh[2], bl[2], alo[2];
#pragma unroll
      for (int ni = 0; ni < 2; ni++) {
        bh[ni] = *(const bf16x8*)(lbase + jb + ni * 1024);
        bl[ni] = *(const bf16x8*)(lbase + jb + 8192 + ni * 1024);
      }
#pragma unroll
      for (int mi = 0; mi < 2; mi++) {
        const int row = wm * 32 + mi * 16 + lrow;
        const int off = row * 256 + (((kf * 4 + lkg) ^ (row & 15)) << 4);
        alo[mi] = *(const bf16x8*)(sAlo + off);
      }
      __builtin_amdgcn_s_setprio(1);
      // term-major: three passes of 4 independent MFMAs
#pragma unroll
      for (int mi = 0; mi < 2; mi++)
#pragma unroll
        for (int ni = 0; ni < 2; ni++)
          acc[mi][ni] = __builtin_amdgcn_mfma_f32_16x16x32_bf16(
              ah[mi][kf], bh[ni], acc[mi][ni], 0, 0, 0);
#pragma unroll
      for (int mi = 0; mi < 2; mi++)
#pragma unroll
        for (int ni = 0; ni < 2; ni++)
          acc[mi][ni] = __builtin_amdgcn_mfma_f32_16x16x32_bf16(
              alo[mi], bh[ni], acc[mi][ni], 0, 0, 0);
#pragma unroll
      for (int mi = 0; mi < 2; mi++)
#pragma unroll
        for (int ni = 0; ni < 2; ni++)
          acc[mi][ni] = __builtin_amdgcn_mfma_f32_16x16x32_bf16(
              ah[mi][kf], bl[ni], acc[mi][ni], 0, 0, 0);
      __builtin_amdgcn_s_setprio(0);
    }
    // in-lane fold (no shuffles): ascending (s,ni) + strict > keeps lowest col
#pragma unroll
    for (int mi = 0; mi < 2; mi++) {
#pragma unroll
      for (int reg = 0; reg < 4; reg++) {
        const int q = mi * 4 + reg;
        float bv = bestv[mi][reg];
#pragma unroll
        for (int ni = 0; ni < 2; ni++) {
          const float x = acc[mi][ni][reg];
          const int col = itembase + wn * 32 + ni * 16 + lrow;
          const bool win = (col < M_ITEMS) && (x > bv);
          bv = win ? x : bv;
          const unsigned code = (unsigned)(s * 4 + ni);
          const unsigned nw = (sel & ~(0xFu << (q * 4))) | (code << (q * 4));
          sel = win ? nw : sel;
        }
        asm volatile("v_accvgpr_write_b32 %0, %1"
                     : "=a"(bestv[mi][reg]) : "v"(bv));
      }
#pragma unroll
      for (int ni = 0; ni < 2; ni++) acc[mi][ni] = (f32x4)(0.0f);
    }
  }
  asm volatile("s_waitcnt vmcnt(0)" ::: "memory");  // drain dummy tail prefetches

  // final fold: ONE butterfly per q; owner lane (lrow==q) keeps its row's key
  unsigned long long rb = 0ull;
#pragma unroll
  for (int mi = 0; mi < 2; mi++) {
#pragma unroll
    for (int reg = 0; reg < 4; reg++) {
      const int q = mi * 4 + reg;
      const unsigned code = (sel >> (q * 4)) & 0xFu;
      float v = bestv[mi][reg];
      int bi = chunk + (int)(code >> 2) * BNI + wn * 32 + (int)(code & 3) * 16 + lrow;
#pragma unroll
      for (int off = 1; off < 16; off <<= 1) {
        float ov = __shfl_xor(v, off, 16);
        int oi = __shfl_xor(bi, off, 16);
        if (ov > v || (ov == v && oi < bi)) { v = ov; bi = oi; }
      }
      if (lrow == q) rb = pack_key(v, bi);
    }
  }
  // lanes lrow<8 each own one distinct row of the wave's 32
  if (lrow < 8) {
    const int myrow = rowbase + wm * 32 + (lrow >> 2) * 16 + lkg * 4 + (lrow & 3);
    atomicMax(&keys[myrow], rb);
  }
}

// ---------- kernel 7: unpack top1, gather, cosine sim ----------
__global__ void k_post(const unsigned long long* __restrict__ keys,
                       const int* __restrict__ uid,
                       const float* __restrict__ items,
                       float* __restrict__ out, float* __restrict__ sims,
                       float* __restrict__ rl) {
  int r = blockIdx.x * blockDim.x + threadIdx.x;
  if (r >= B_ROWS) return;
  unsigned long long key = keys[r];
  int idx = (int)(~(unsigned)(key & 0xFFFFFFFFull));
  out[r] = (float)idx;
  int orig = uid[2 * r + 1];
  const float* a = items + (long long)orig * D_DIM;
  const float* c = items + (long long)idx * D_DIM;
  float aa = 0.f, cc = 0.f, ac = 0.f;
#pragma unroll 4
  for (int d = 0; d < D_DIM; d++) {
    float x = a[d], y = c[d];
    aa = fmaf(x, x, aa);
    cc = fmaf(y, y, cc);
    ac = fmaf(x, y, ac);
  }
  float na = fmaxf(sqrtf(aa), COS_EPS_F);
  float nc = fmaxf(sqrtf(cc), COS_EPS_F);
  float sim = ac / (na * nc);
  sim = (sim + 1.f) * 0.5f;
  sims[r] = sim;
  rl[r] = fmaxf(sim - 0.5f, 0.f);
}

// ---------- kernel 8: deterministic final means ----------
__global__ void k_final(const float* __restrict__ sims, const float* __restrict__ rl,
                        float* __restrict__ out) {
  __shared__ float s1[256], s2[256];
  int t = threadIdx.x;
  float a = 0.f, b = 0.f;
  for (int r = t; r < B_ROWS; r += 256) { a += rl[r]; b += sims[r]; }
  s1[t] = a; s2[t] = b;
  __syncthreads();
  for (int off = 128; off; off >>= 1) {
    if (t < off) { s1[t] += s1[t + off]; s2[t] += s2[t + off]; }
    __syncthreads();
  }
  if (t == 0) {
    out[B_ROWS] = s1[0] / (float)B_ROWS;
    out[B_ROWS + 1] = s2[0] / (float)B_ROWS;
  }
}

extern "C" void kernel_launch(void* const* d_in, const int* in_sizes, int n_in,
                              void* d_out, int out_size, void* d_ws, size_t ws_size,
                              hipStream_t stream) {
  const float* item_feature = (const float*)d_in[0];
  const float* all_items    = (const float*)d_in[1];
  const int*   uid          = (const int*)d_in[2];
  const float* W            = (const float*)d_in[3];
  const float* bias         = (const float*)d_in[4];
  const float* gamma        = (const float*)d_in[5];
  const float* beta         = (const float*)d_in[6];
  float* out = (float*)d_out;

  float* h     = (float*)d_ws;             // 2048*128
  float* scale = h + B_ROWS * D_DIM;       // 128
  float* shift = scale + D_DIM;            // 128
  unsigned long long* keys = (unsigned long long*)(shift + D_DIM);  // 2048
  float* sims  = (float*)(keys + B_ROWS);  // 2048
  float* rl    = sims + B_ROWS;            // 2048

  k_gemm1<<<B_ROWS, D_DIM, 0, stream>>>(item_feature, W, bias, h);
  k_bnstats<<<D_DIM, 256, 0, stream>>>(h, gamma, beta, scale, shift);
  k_norm_split<<<(B_ROWS * D_DIM + 255) / 256, 256, 0, stream>>>(h, scale, shift);
  k_build_items<<<(M_PAD * D_DIM / 4 + 255) / 256, 256, 0, stream>>>(all_items);
  k_init<<<(B_ROWS + 255) / 256, 256, 0, stream>>>(keys);
  dim3 sg(B_ROWS / BROWS, M_PAD / (SUPER * BNI));  // x = row-block (fast), y = item chunk
  k_scores_mfma<<<sg, 512, 0, stream>>>(keys);
  k_post<<<(B_ROWS + 255) / 256, 256, 0, stream>>>(keys, uid, all_items, out, sims, rl);
  k_final<<<1, 256, 0, stream>>>(sims, rl, out);
}